// Round 5
// baseline (77.091 us; speedup 1.0000x reference)
//
#include <hip/hip_runtime.h>
#include <hip/hip_bf16.h>

#define B 2
#define C 64
#define N 4096          // 16*16*16
#define EPS 1e-5f
// 0.125 * log2(e): fold softmax scale AND exp->exp2 conversion into q
#define QSCALE_LOG2E 0.18033688f

using short8 = __attribute__((ext_vector_type(8))) short;
using f32x16 = __attribute__((ext_vector_type(16))) float;

__device__ inline short f2bf(float f) {
  __hip_bfloat16 h = __float2bfloat16(f);
  union { __hip_bfloat16 h; short s; } u; u.h = h; return u.s;
}
__device__ inline float bf2f(short s) {
  union { unsigned u; float f; } u;
  u.u = ((unsigned)(unsigned short)s) << 16;
  return u.f;
}
__device__ inline int packbf(float a, float b) {
  return (int)((unsigned short)f2bf(a) | ((unsigned)(unsigned short)f2bf(b) << 16));
}

// ---------------- GroupNorm partial sums ----------------
// grid 512 = 32 (b,g) x 16 slices, 256 thr, 1 float4/thread -> all CUs on HBM.
__global__ __launch_bounds__(256) void gn_part_kernel(
    const float* __restrict__ x, float2* __restrict__ part) {
  int blk = blockIdx.x;
  int bg = blk >> 4, sl = blk & 15;
  const float4* xv = (const float4*)(x + (size_t)bg * 4 * N) + sl * 256;
  int tid = threadIdx.x;
  float4 v = xv[tid];
  float s = v.x + v.y + v.z + v.w;
  float s2 = v.x * v.x + v.y * v.y + v.z * v.z + v.w * v.w;
  __shared__ float ss[256], ss2[256];
  ss[tid] = s; ss2[tid] = s2;
  __syncthreads();
  for (int st = 128; st > 0; st >>= 1) {
    if (tid < st) { ss[tid] += ss[tid + st]; ss2[tid] += ss2[tid + st]; }
    __syncthreads();
  }
  if (tid == 0) part[blk] = make_float2(ss[0], ss2[0]);
}

// ---------------- GroupNorm finalize: per-channel scale/shift ----------------
// 1 block, 128 threads: t = b*64 + c
__global__ __launch_bounds__(128) void gn_final_kernel(
    const float2* __restrict__ part, const float* __restrict__ gw,
    const float* __restrict__ gb, float* __restrict__ ascale,
    float* __restrict__ bshift) {
  int t = threadIdx.x;
  int c = t & 63, b = t >> 6, g = c >> 2;
  int bg = b * 16 + g;
  float s = 0.f, s2 = 0.f;
#pragma unroll
  for (int sl = 0; sl < 16; ++sl) {
    float2 p = part[bg * 16 + sl];
    s += p.x; s2 += p.y;
  }
  float mean = s * (1.f / 16384.f);
  float var = s2 * (1.f / 16384.f) - mean * mean;
  float inv = rsqrtf(var + EPS);
  float a = inv * gw[c];
  ascale[t] = a;
  bshift[t] = gb[c] - mean * a;
}

// ---------------- fused norm + q/k/v conv (8 outputs/block) ----------------
// q_t,k_t: bf16 [b][pos][ch] (q pre-scaled by 0.125*log2e); v: bf16 [b][ch][pos]
__global__ __launch_bounds__(256) void qkv_kernel(
    const float* __restrict__ x, const float* __restrict__ ascale,
    const float* __restrict__ bshift,
    const float* __restrict__ qw, const float* __restrict__ qb,
    const float* __restrict__ kw, const float* __restrict__ kb,
    const float* __restrict__ vw, const float* __restrict__ vb,
    short* __restrict__ q_t, short* __restrict__ k_t, short* __restrict__ v_b) {
  int o0 = blockIdx.y * 8, b = blockIdx.z;
  int pos = blockIdx.x * 256 + threadIdx.x;
  const float* xp = x + (size_t)b * C * N + pos;
  const float* as = ascale + b * C;
  const float* bs = bshift + b * C;

  float sq[8], sk[8], sv[8];
#pragma unroll
  for (int j = 0; j < 8; ++j) { sq[j] = 0.f; sk[j] = 0.f; sv[j] = 0.f; }
#pragma unroll
  for (int c = 0; c < C; ++c) {
    float hv = fmaf(xp[(size_t)c * N], as[c], bs[c]);
#pragma unroll
    for (int j = 0; j < 8; ++j) {
      sq[j] = fmaf(qw[(o0 + j) * C + c], hv, sq[j]);
      sk[j] = fmaf(kw[(o0 + j) * C + c], hv, sk[j]);
      sv[j] = fmaf(vw[(o0 + j) * C + c], hv, sv[j]);
    }
  }
  size_t ti = ((size_t)b * N + pos) * C;
  short8 qv, kv;
#pragma unroll
  for (int j = 0; j < 8; ++j) {
    qv[j] = f2bf((sq[j] + qb[o0 + j]) * QSCALE_LOG2E);
    kv[j] = f2bf(sk[j] + kb[o0 + j]);
  }
  *(short8*)&q_t[ti + o0] = qv;
  *(short8*)&k_t[ti + o0] = kv;
#pragma unroll
  for (int j = 0; j < 8; ++j)
    v_b[((size_t)b * C + o0 + j) * N + pos] = f2bf(sv[j] + vb[o0 + j]);
}

// softmax (exp2 domain, no max) + pack P into two PV B-fragments
__device__ inline void softpack(f32x16& s, int hi, float& lsum,
                                short8& p0, short8& p1) {
  float ps = 0.f;
#pragma unroll
  for (int i = 0; i < 16; ++i) { s[i] = exp2f(s[i]); ps += s[i]; }
  lsum += ps;   // cross-pair shfl deferred to epilogue (linear)
  union U { int i[4]; short8 v; } f0, f1;
  {
    int x0 = packbf(s[0], s[1]), z0 = packbf(s[2], s[3]);
    int y0 = packbf(s[4], s[5]), w0 = packbf(s[6], s[7]);
    int xs = __shfl_xor(x0, 32), zs = __shfl_xor(z0, 32);
    int ys = __shfl_xor(y0, 32), ws2 = __shfl_xor(w0, 32);
    f0.i[0] = hi ? ys : x0; f0.i[1] = hi ? ws2 : z0;
    f0.i[2] = hi ? y0 : xs; f0.i[3] = hi ? w0 : zs;
  }
  {
    int x0 = packbf(s[8], s[9]), z0 = packbf(s[10], s[11]);
    int y0 = packbf(s[12], s[13]), w0 = packbf(s[14], s[15]);
    int xs = __shfl_xor(x0, 32), zs = __shfl_xor(z0, 32);
    int ys = __shfl_xor(y0, 32), ws2 = __shfl_xor(w0, 32);
    f1.i[0] = hi ? ys : x0; f1.i[1] = hi ? ws2 : z0;
    f1.i[2] = hi ? y0 : xs; f1.i[3] = hi ? w0 : zs;
  }
  p0 = f0.v; p1 = f1.v;
}

// ---------------- MFMA flash attention, double-buffered prefetch ----------
// grid (N/256, kseg, B), block 256 = 4 independent waves, 64 queries each.
__global__ __launch_bounds__(256) void attn_kernel(
    const short* __restrict__ q_t, const short* __restrict__ k_t,
    const short* __restrict__ v_b, short* __restrict__ opart,
    float* __restrict__ lpart, int segLen, int kseg) {
  int b = blockIdx.z, s = blockIdx.y;
  int l = threadIdx.x & 63;
  int q0 = blockIdx.x * 256 + (threadIdx.x >> 6) * 64;
  int lo5 = l & 31;
  int hi = l >> 5;

  const short* qp = q_t + (size_t)b * N * C;
  const short* kp = k_t + (size_t)b * N * C;
  const short* vp = v_b + (size_t)b * C * N;

  short8 qf[2][4];
#pragma unroll
  for (int qt = 0; qt < 2; ++qt)
#pragma unroll
    for (int t = 0; t < 4; ++t)
      qf[qt][t] = *(const short8*)&qp[(size_t)(q0 + qt * 32 + lo5) * C + t * 16 + hi * 8];

  f32x16 oacc00, oacc01, oacc10, oacc11;   // [qt][c-half]
#pragma unroll
  for (int i = 0; i < 16; ++i) { oacc00[i] = 0.f; oacc01[i] = 0.f; oacc10[i] = 0.f; oacc11[i] = 0.f; }
  float lsum[2] = {0.f, 0.f};

  int kbase = s * segLen;

  // fragment-load helpers (lane pattern validated R1-R4)
#define LOAD_KF(DST, K0)                                                     \
  _Pragma("unroll") for (int t = 0; t < 4; ++t)                              \
      DST[t] = *(const short8*)&kp[(size_t)((K0) + lo5) * C + t * 16 + hi * 8];
#define LOAD_VF(DST, K0)                                                     \
  DST[0] = *(const short8*)&vp[(size_t)(lo5) * N + (K0) + hi * 8];           \
  DST[1] = *(const short8*)&vp[(size_t)(32 + lo5) * N + (K0) + hi * 8];      \
  DST[2] = *(const short8*)&vp[(size_t)(lo5) * N + (K0) + 16 + hi * 8];      \
  DST[3] = *(const short8*)&vp[(size_t)(32 + lo5) * N + (K0) + 16 + hi * 8];

// compute one 32-key chunk from registers KF/VF
#define CHUNK(KF, VF)                                                        \
  {                                                                          \
    f32x16 s0_, s1_;                                                         \
    _Pragma("unroll") for (int i = 0; i < 16; ++i) { s0_[i] = 0.f; s1_[i] = 0.f; } \
    __builtin_amdgcn_s_setprio(1);                                           \
    _Pragma("unroll") for (int t = 0; t < 4; ++t) {                          \
      s0_ = __builtin_amdgcn_mfma_f32_32x32x16_bf16(KF[t], qf[0][t], s0_, 0, 0, 0); \
      s1_ = __builtin_amdgcn_mfma_f32_32x32x16_bf16(KF[t], qf[1][t], s1_, 0, 0, 0); \
    }                                                                        \
    __builtin_amdgcn_s_setprio(0);                                           \
    short8 pf00, pf01, pf10, pf11;                                           \
    softpack(s0_, hi, lsum[0], pf00, pf01);                                  \
    softpack(s1_, hi, lsum[1], pf10, pf11);                                  \
    __builtin_amdgcn_s_setprio(1);                                           \
    oacc00 = __builtin_amdgcn_mfma_f32_32x32x16_bf16(VF[0], pf00, oacc00, 0, 0, 0); \
    oacc01 = __builtin_amdgcn_mfma_f32_32x32x16_bf16(VF[1], pf00, oacc01, 0, 0, 0); \
    oacc10 = __builtin_amdgcn_mfma_f32_32x32x16_bf16(VF[0], pf10, oacc10, 0, 0, 0); \
    oacc11 = __builtin_amdgcn_mfma_f32_32x32x16_bf16(VF[1], pf10, oacc11, 0, 0, 0); \
    oacc00 = __builtin_amdgcn_mfma_f32_32x32x16_bf16(VF[2], pf01, oacc00, 0, 0, 0); \
    oacc01 = __builtin_amdgcn_mfma_f32_32x32x16_bf16(VF[3], pf01, oacc01, 0, 0, 0); \
    oacc10 = __builtin_amdgcn_mfma_f32_32x32x16_bf16(VF[2], pf11, oacc10, 0, 0, 0); \
    oacc11 = __builtin_amdgcn_mfma_f32_32x32x16_bf16(VF[3], pf11, oacc11, 0, 0, 0); \
    __builtin_amdgcn_s_setprio(0);                                           \
  }

  short8 kf0[4], kf1[4], vf0[4], vf1[4];
  LOAD_KF(kf0, kbase)
  LOAD_VF(vf0, kbase)

  // segLen/64 iterations, two chunks each, cross-iteration prefetch
  for (int kc = 0; kc < segLen; kc += 64) {
    int kA = kbase + kc;
    // prefetch chunk kA+32 into buffer 1
    LOAD_KF(kf1, kA + 32)
    LOAD_VF(vf1, kA + 32)
    CHUNK(kf0, vf0)
    // prefetch chunk kA+64 into buffer 0 (clamped on last iteration)
    int kN = (kc + 64 < segLen) ? (kA + 64) : kA;
    LOAD_KF(kf0, kN)
    LOAD_VF(vf0, kN)
    CHUNK(kf1, vf1)
  }

#pragma unroll
  for (int qt = 0; qt < 2; ++qt) {
    lsum[qt] += __shfl_xor(lsum[qt], 32);
    int qq = q0 + qt * 32 + lo5;
    short* op = opart + (size_t)(b * kseg + s) * C * N;
#pragma unroll
    for (int r = 0; r < 16; ++r) {
      int c = (r & 3) + 8 * (r >> 2) + 4 * hi;
      float v0 = (qt == 0) ? oacc00[r] : oacc10[r];
      float v1 = (qt == 0) ? oacc01[r] : oacc11[r];
      op[(size_t)c * N + qq] = f2bf(v0);
      op[(size_t)(c + 32) * N + qq] = f2bf(v1);
    }
    if (hi == 0) lpart[(size_t)(b * kseg + s) * N + qq] = lsum[qt];
  }
#undef LOAD_KF
#undef LOAD_VF
#undef CHUNK
}

// ---------------- merge segments (pure sum, no exp) ----------------
__global__ __launch_bounds__(256) void merge_kernel(
    const short* __restrict__ opart, const float* __restrict__ lpart,
    short* __restrict__ attnout, int kseg) {
  int idx = blockIdx.x * 256 + threadIdx.x;
  int q4 = (idx & 1023) * 4;
  int c = (idx >> 10) & 63;
  int b = idx >> 16;

  float o[4] = {0.f, 0.f, 0.f, 0.f};
  float L[4] = {0.f, 0.f, 0.f, 0.f};
  for (int s = 0; s < kseg; ++s) {
    float4 lv = *(const float4*)&lpart[(size_t)(b * kseg + s) * N + q4];
    L[0] += lv.x; L[1] += lv.y; L[2] += lv.z; L[3] += lv.w;
    short4 ov = *(const short4*)&opart[((size_t)(b * kseg + s) * C + c) * N + q4];
    o[0] += bf2f(ov.x); o[1] += bf2f(ov.y); o[2] += bf2f(ov.z); o[3] += bf2f(ov.w);
  }
  short4 r;
  r.x = f2bf(o[0] / L[0]); r.y = f2bf(o[1] / L[1]);
  r.z = f2bf(o[2] / L[2]); r.w = f2bf(o[3] / L[3]);
  *(short4*)&attnout[(size_t)(b * C + c) * N + q4] = r;
}

// ---------------- proj conv + residual (8 outputs/block) ----------------
__global__ __launch_bounds__(256) void proj_kernel(
    const short* __restrict__ at, const float* __restrict__ pw,
    const float* __restrict__ pb, const float* __restrict__ x,
    float* __restrict__ out) {
  int o0 = blockIdx.y * 8, b = blockIdx.z;
  int pos = blockIdx.x * 256 + threadIdx.x;
  const short* h = at + (size_t)b * C * N + pos;
  float sum[8];
#pragma unroll
  for (int j = 0; j < 8; ++j) sum[j] = 0.f;
#pragma unroll
  for (int c = 0; c < C; ++c) {
    float hv = bf2f(h[(size_t)c * N]);
#pragma unroll
    for (int j = 0; j < 8; ++j) sum[j] = fmaf(pw[(o0 + j) * C + c], hv, sum[j]);
  }
#pragma unroll
  for (int j = 0; j < 8; ++j) {
    size_t oi = (size_t)(b * C + o0 + j) * N + pos;
    out[oi] = x[oi] + sum[j] + pb[o0 + j];
  }
}

extern "C" void kernel_launch(void* const* d_in, const int* in_sizes, int n_in,
                              void* d_out, int out_size, void* d_ws, size_t ws_size,
                              hipStream_t stream) {
  const float* x      = (const float*)d_in[0];
  const float* norm_w = (const float*)d_in[1];
  const float* norm_b = (const float*)d_in[2];
  const float* q_w    = (const float*)d_in[3];
  const float* q_b    = (const float*)d_in[4];
  const float* k_w    = (const float*)d_in[5];
  const float* k_b    = (const float*)d_in[6];
  const float* v_w    = (const float*)d_in[7];
  const float* v_b    = (const float*)d_in[8];
  const float* proj_w = (const float*)d_in[9];
  const float* proj_b = (const float*)d_in[10];
  float* out = (float*)d_out;

  const size_t BCN = (size_t)B * C * N;   // 524288

  int kseg = 16;
  auto need = [&](int s) -> size_t {
    return BCN * 2 * 4                              // q,k,v,attnout bf16
         + (2 * B * C + 1024 + (size_t)s * B * N) * 4   // ascale,bshift,part,lpart
         + (size_t)s * BCN * 2;                     // opart bf16
  };
  while (kseg > 1 && need(kseg) > ws_size) kseg >>= 1;
  int segLen = N / kseg;

  short* q_t     = (short*)d_ws;
  short* k_t     = q_t + BCN;
  short* vbuf    = k_t + BCN;
  short* attnout = vbuf + BCN;
  float* ascale  = (float*)(attnout + BCN);
  float* bshift  = ascale + B * C;
  float2* part   = (float2*)(bshift + B * C);     // 512 float2
  float* lpart   = (float*)(part + 512);
  short* opart   = (short*)(lpart + (size_t)kseg * B * N);

  gn_part_kernel<<<512, 256, 0, stream>>>(x, part);
  gn_final_kernel<<<1, 128, 0, stream>>>(part, norm_w, norm_b, ascale, bshift);

  qkv_kernel<<<dim3(N / 256, C / 8, B), 256, 0, stream>>>(
      x, ascale, bshift, q_w, q_b, k_w, k_b, v_w, v_b, q_t, k_t, vbuf);

  attn_kernel<<<dim3(N / 256, kseg, B), 256, 0, stream>>>(
      q_t, k_t, vbuf, opart, lpart, segLen, kseg);

  merge_kernel<<<(int)(BCN / 4 / 256), 256, 0, stream>>>(
      opart, lpart, attnout, kseg);

  proj_kernel<<<dim3(N / 256, C / 8, B), 256, 0, stream>>>(
      attnout, proj_w, proj_b, x, out);
}